// Round 11
// baseline (392.844 us; speedup 1.0000x reference)
//
#include <hip/hip_runtime.h>

// Problem constants (match reference setup_inputs)
constexpr int N_NODES = 50000;
constexpr int N_EDGES = 25000;
constexpr int C = 256;   // IN == OUT == 256 channels
constexpr int L = 32;    // incidence list width

// Transposed bf16 weights in device globals.
__device__ ushort W1T_g[C * C];   // [n][k] bf16
__device__ ushort W2T_g[C * C];   // [n][k] bf16

// Native clang vector types (usable with nontemporal builtins).
typedef __attribute__((ext_vector_type(8))) short bf16x8;
typedef __attribute__((ext_vector_type(4))) float f32x4;

__device__ __forceinline__ ushort f2bf(float f) {
    union { float f; unsigned int u; } c; c.f = f;
    unsigned int r = c.u + 0x7FFFu + ((c.u >> 16) & 1u);   // RNE
    return (ushort)(r >> 16);
}
// bf16 pair unpack: low half = shift, high half = mask (1 VALU op each)
__device__ __forceinline__ float bflo(unsigned int u) {
    union { unsigned int x; float f; } c; c.x = u << 16; return c.f;
}
__device__ __forceinline__ float bfhi(unsigned int u) {
    union { unsigned int x; float f; } c; c.x = u & 0xFFFF0000u; return c.f;
}
__device__ __forceinline__ void acc_uint4(float* acc, const uint4 v) {
    acc[0] += bflo(v.x); acc[1] += bfhi(v.x);
    acc[2] += bflo(v.y); acc[3] += bfhi(v.y);
    acc[4] += bflo(v.z); acc[5] += bfhi(v.z);
    acc[6] += bflo(v.w); acc[7] += bfhi(v.w);
}

// ---------------------------------------------------------------------------
// x [N,256] fp32 -> xb bf16. 4 elems/thread.
// ---------------------------------------------------------------------------
__global__ __launch_bounds__(256) void convert_x_kernel(
    const float* __restrict__ x, ushort* __restrict__ xb)
{
    const size_t i = ((size_t)blockIdx.x * 256 + threadIdx.x) * 4;
    const float4 v = *reinterpret_cast<const float4*>(x + i);
    ushort4 o;
    o.x = f2bf(v.x); o.y = f2bf(v.y); o.z = f2bf(v.z); o.w = f2bf(v.w);
    *reinterpret_cast<ushort4*>(xb + i) = o;
}

// ---------------------------------------------------------------------------
// W [256k,256n] fp32 row-major -> WT [n][k] bf16 (transposed), via LDS tile.
// ---------------------------------------------------------------------------
__global__ __launch_bounds__(256) void wconv_kernel(
    const float* __restrict__ W1, const float* __restrict__ W2)
{
    const float* W  = blockIdx.z ? W2 : W1;
    ushort* WT      = blockIdx.z ? W2T_g : W1T_g;
    __shared__ float t[64][65];
    const int rr = threadIdx.x >> 6;    // 0..3
    const int cc = threadIdx.x & 63;    // 0..63
    const int br = blockIdx.x * 64;     // k tile
    const int bc = blockIdx.y * 64;     // n tile
#pragma unroll
    for (int i = 0; i < 16; ++i) {
        const int row = i * 4 + rr;
        t[row][cc] = W[(size_t)(br + row) * C + bc + cc];
    }
    __syncthreads();
#pragma unroll
    for (int i = 0; i < 16; ++i) {
        const int n = i * 4 + rr;
        WT[(size_t)(bc + n) * C + br + cc] = f2bf(t[cc][n]);
    }
}

// ---------------------------------------------------------------------------
// FUSED gather+GEMM (R9/R10-verified; EDGE side only):
//   stage idx -> gather-avg 32 full src rows -> bf16 A-tile [32][264] LDS
//   -> 4 waves MFMA A @ W1T -> RELU+bf16 out.
// (Node-side fusion rejected in R9: losing 64ch chunking pushed 819MB of
// gathers out of L2, FETCH 26MB->282MB, +18us.)
// ---------------------------------------------------------------------------
constexpr int BR = 32;        // output rows per block
constexpr int APITCH = 264;   // bf16 elems per A_lds row (256 + 8 pad)

template <bool RELU, bool OUT_F32>
__global__ __launch_bounds__(256) void fused_gather_gemm_kernel(
    const ushort* __restrict__ src, const int* __restrict__ idx,
    int which_w, ushort* __restrict__ dstb, float* __restrict__ dstf, int M)
{
    const ushort* __restrict__ BT = which_w ? W2T_g : W1T_g;
    const int t  = threadIdx.x;
    const int rb = blockIdx.x * BR;

    __shared__ int    sidx[BR][33];
    __shared__ ushort A_lds[BR][APITCH];

    // ---- stage indices: BR*L = 1024 ints, 4 per thread
#pragma unroll
    for (int i = 0; i < (BR * L) / 256; ++i) {
        const int flat = i * 256 + t;
        const int r = flat >> 5, l = flat & 31;
        sidx[r][l] = (rb + r < M) ? idx[(size_t)(rb + r) * L + l] : 0;
    }
    __syncthreads();

    // ---- gather phase: half-wave (32 lanes) per row, 512B granule, 4 passes
    const int hw = t >> 5;     // 0..7
    const int ln = t & 31;     // channel group: 8 bf16 = 16B per lane

    const uint4 v0 = *reinterpret_cast<const uint4*>(src + ln * 8); // row 0
    float x0[8];
    x0[0] = bflo(v0.x); x0[1] = bfhi(v0.x); x0[2] = bflo(v0.y); x0[3] = bfhi(v0.y);
    x0[4] = bflo(v0.z); x0[5] = bfhi(v0.z); x0[6] = bflo(v0.w); x0[7] = bfhi(v0.w);

#pragma unroll
    for (int p = 0; p < 4; ++p) {
        const int r = p * 8 + hw;
        float acc[8] = {0.f, 0.f, 0.f, 0.f, 0.f, 0.f, 0.f, 0.f};
        int cnt = 0;
#pragma unroll
        for (int lb = 0; lb < L; lb += 8) {
            uint4 v[8];
#pragma unroll
            for (int j = 0; j < 8; ++j) {
                const int id = sidx[r][lb + j];
                cnt += (id > 0) ? 1 : 0;
                v[j] = *reinterpret_cast<const uint4*>(
                    src + (size_t)id * C + ln * 8);
            }
#pragma unroll
            for (int j = 0; j < 8; ++j) acc_uint4(acc, v[j]);
        }
        const float corr = (cnt == 0) ? 0.f : (float)(L - cnt);
        const float inv  = (cnt == 0) ? (1.f / (float)L) : (1.f / (float)cnt);
        uint4 o;
        o.x = (unsigned)f2bf((acc[0] - corr * x0[0]) * inv) |
              ((unsigned)f2bf((acc[1] - corr * x0[1]) * inv) << 16);
        o.y = (unsigned)f2bf((acc[2] - corr * x0[2]) * inv) |
              ((unsigned)f2bf((acc[3] - corr * x0[3]) * inv) << 16);
        o.z = (unsigned)f2bf((acc[4] - corr * x0[4]) * inv) |
              ((unsigned)f2bf((acc[5] - corr * x0[5]) * inv) << 16);
        o.w = (unsigned)f2bf((acc[6] - corr * x0[6]) * inv) |
              ((unsigned)f2bf((acc[7] - corr * x0[7]) * inv) << 16);
        *reinterpret_cast<uint4*>(&A_lds[r][ln * 8]) = o;
    }
    __syncthreads();

    // ---- GEMM phase: wave w covers cols w*64 .. w*64+63
    const int wave = t >> 6;
    const int lane = t & 63;
    const int quad = lane >> 4;
    const int l16  = lane & 15;

    f32x4 acc2[2][4];
    const f32x4 zero = {0.f, 0.f, 0.f, 0.f};
#pragma unroll
    for (int p = 0; p < 2; ++p)
#pragma unroll
        for (int tt = 0; tt < 4; ++tt) acc2[p][tt] = zero;

    const ushort* br = BT + (size_t)(wave * 64 + l16) * C + quad * 8;

#pragma unroll
    for (int k0 = 0; k0 < C; k0 += 32) {
        const bf16x8 a0 = *reinterpret_cast<const bf16x8*>(&A_lds[l16][quad * 8 + k0]);
        const bf16x8 a1 = *reinterpret_cast<const bf16x8*>(&A_lds[16 + l16][quad * 8 + k0]);
#pragma unroll
        for (int tt = 0; tt < 4; ++tt) {
            const bf16x8 b = *reinterpret_cast<const bf16x8*>(
                br + (size_t)tt * 16 * C + k0);
            acc2[0][tt] = __builtin_amdgcn_mfma_f32_16x16x32_bf16(a0, b, acc2[0][tt], 0, 0, 0);
            acc2[1][tt] = __builtin_amdgcn_mfma_f32_16x16x32_bf16(a1, b, acc2[1][tt], 0, 0, 0);
        }
    }

    // ---- epilogue (C/D layout: col=l16, row=quad*4+r -- m89-verified)
#pragma unroll
    for (int p = 0; p < 2; ++p)
#pragma unroll
    for (int tt = 0; tt < 4; ++tt)
#pragma unroll
    for (int r = 0; r < 4; ++r) {
        const int gm = rb + p * 16 + quad * 4 + r;
        if (gm < M) {
            float v = acc2[p][tt][r];
            if (RELU) v = fmaxf(v, 0.f);
            const int col = wave * 64 + tt * 16 + l16;
            if constexpr (OUT_F32) {
                __builtin_nontemporal_store(v, dstf + (size_t)gm * C + col);
            } else {
                dstb[(size_t)gm * C + col] = f2bf(v);
            }
        }
    }
}

// ---------------------------------------------------------------------------
// gather_node: out[row, chunk*64 .. +64] fp32. Chunked (L2-resident slices),
// batch-8 loads, NT stores -- all R8/R10-verified.
// R11 EXPERIMENT: block 256 -> 1024 threads (16 waves/block, RPB 32->128).
// Occupancy counter pinned at ~19% (~6 waves/CU) across all variants while
// the latency model needs more in-flight lines; 16-wave blocks give >=16
// waves/CU even at 1 resident block. Single-variable test of whether the
// in-flight cap is block-scheduling (fix works) or per-CU MSHR (neutral).
// ---------------------------------------------------------------------------
__global__ __launch_bounds__(1024) void gather_node_kernel(
    const ushort* __restrict__ src, const int* __restrict__ idx,
    float* __restrict__ dst, int nrows)
{
    constexpr int BLK = 1024;
    constexpr int CH = 64, NCHUNK = 4;
    constexpr int LPR = CH / 8;        // 8 lanes per row
    constexpr int RPB = BLK / LPR;     // 128 rows per block
    const int chunk = blockIdx.x & (NCHUNK - 1);
    const int rb    = (int)(blockIdx.x / NCHUNK) * RPB;
    const int t     = threadIdx.x;

    __shared__ int sidx[RPB][33];
#pragma unroll
    for (int i = 0; i < (RPB * L) / BLK; ++i) {
        const int flat = i * BLK + t;
        const int r = flat >> 5, l = flat & 31;
        sidx[r][l] = (rb + r < nrows) ? idx[(size_t)(rb + r) * L + l] : 0;
    }
    __syncthreads();

    const int r   = t / LPR;
    const int ch  = chunk * CH + (t % LPR) * 8;
    const int row = rb + r;
    if (row >= nrows) return;

    float acc[8] = {0.f, 0.f, 0.f, 0.f, 0.f, 0.f, 0.f, 0.f};
    int cnt = 0;
#pragma unroll
    for (int lb = 0; lb < L; lb += 8) {
        uint4 v[8];
#pragma unroll
        for (int j = 0; j < 8; ++j) {
            const int id = sidx[r][lb + j];
            cnt += (id > 0) ? 1 : 0;
            v[j] = *reinterpret_cast<const uint4*>(
                src + (size_t)id * C + ch);
        }
#pragma unroll
        for (int j = 0; j < 8; ++j) acc_uint4(acc, v[j]);
    }
    const uint4 v0 = *reinterpret_cast<const uint4*>(src + ch);  // row 0
    float x0[8];
    x0[0] = bflo(v0.x); x0[1] = bfhi(v0.x); x0[2] = bflo(v0.y); x0[3] = bfhi(v0.y);
    x0[4] = bflo(v0.z); x0[5] = bfhi(v0.z); x0[6] = bflo(v0.w); x0[7] = bfhi(v0.w);

    const float corr = (cnt == 0) ? 0.f : (float)(L - cnt);
    const float inv  = (cnt == 0) ? (1.f / (float)L) : (1.f / (float)cnt);

    float* d = dst + (size_t)row * C + ch;
    f32x4 o0 = {(acc[0] - corr * x0[0]) * inv, (acc[1] - corr * x0[1]) * inv,
                (acc[2] - corr * x0[2]) * inv, (acc[3] - corr * x0[3]) * inv};
    f32x4 o1 = {(acc[4] - corr * x0[4]) * inv, (acc[5] - corr * x0[5]) * inv,
                (acc[6] - corr * x0[6]) * inv, (acc[7] - corr * x0[7]) * inv};
    __builtin_nontemporal_store(o0, reinterpret_cast<f32x4*>(d));
    __builtin_nontemporal_store(o1, reinterpret_cast<f32x4*>(d) + 1);
}

// ---------------------------------------------------------------------------
// MFMA bf16 GEMM (R8-verified): C[M,256] = A[M,256] @ W, WT bf16 [n][k].
// Wave tile 32x128; grid (ceil(M/128), 2).
// ---------------------------------------------------------------------------
template <bool RELU>
__global__ __launch_bounds__(256) void gemm_mfma_kernel(
    const ushort* __restrict__ A, int which_w,
    ushort* __restrict__ Cmat, int M)
{
    const ushort* __restrict__ BT = which_w ? W2T_g : W1T_g;
    const int wave  = threadIdx.x >> 6;
    const int lane  = threadIdx.x & 63;
    const int quad  = lane >> 4;
    const int l16   = lane & 15;
    const int base  = (blockIdx.x * 4 + wave) * 32;
    const int nbase = blockIdx.y * 128;

    int m0 = base + l16;      if (m0 > M - 1) m0 = M - 1;
    int m1 = base + 16 + l16; if (m1 > M - 1) m1 = M - 1;

    f32x4 acc[2][8];
    const f32x4 zero = {0.f, 0.f, 0.f, 0.f};
#pragma unroll
    for (int p = 0; p < 2; ++p)
#pragma unroll
        for (int t = 0; t < 8; ++t) acc[p][t] = zero;

    const ushort* a0 = A + (size_t)m0 * C + quad * 8;
    const ushort* a1 = A + (size_t)m1 * C + quad * 8;
    const ushort* br = BT + (size_t)(nbase + l16) * C + quad * 8;

#pragma unroll
    for (int k0 = 0; k0 < C; k0 += 32) {
        const bf16x8 av0 = *reinterpret_cast<const bf16x8*>(a0 + k0);
        const bf16x8 av1 = *reinterpret_cast<const bf16x8*>(a1 + k0);
#pragma unroll
        for (int t = 0; t < 8; ++t) {
            const bf16x8 b = *reinterpret_cast<const bf16x8*>(
                br + (size_t)t * 16 * C + k0);
            acc[0][t] = __builtin_amdgcn_mfma_f32_16x16x32_bf16(av0, b, acc[0][t], 0, 0, 0);
            acc[1][t] = __builtin_amdgcn_mfma_f32_16x16x32_bf16(av1, b, acc[1][t], 0, 0, 0);
        }
    }

#pragma unroll
    for (int p = 0; p < 2; ++p)
#pragma unroll
    for (int t = 0; t < 8; ++t)
#pragma unroll
    for (int r = 0; r < 4; ++r) {
        const int gm = base + p * 16 + quad * 4 + r;
        if (gm < M) {
            float v = acc[p][t][r];
            if (RELU) v = fmaxf(v, 0.f);
            Cmat[(size_t)gm * C + nbase + t * 16 + l16] = f2bf(v);
        }
    }
}

// ---------------------------------------------------------------------------
// Pipeline (R10 hybrid + R11 gather_node block-size experiment):
//   xb   = bf16(x)                                   [N,256]
//   edge = relu(avg(xb[seq]) @ W1)                   [E,256] bf16  (FUSED)
//   e1   = edge @ W2                                 [E,256] bf16  (GEMM)
//   out  = avg(e1[useq])                             [N,256] fp32  (chunked)
// ws: xb 25.6MB + edge 12.8MB + e1 12.8MB = 51.2MB. 5 dispatches.
// ---------------------------------------------------------------------------
extern "C" void kernel_launch(void* const* d_in, const int* in_sizes, int n_in,
                              void* d_out, int out_size, void* d_ws, size_t ws_size,
                              hipStream_t stream) {
    const float* x    = (const float*)d_in[0];
    const int*   seq  = (const int*)d_in[1];
    const int*   useq = (const int*)d_in[2];
    const float* W1   = (const float*)d_in[3];
    const float* W2   = (const float*)d_in[4];
    float* out = (float*)d_out;

    ushort* xb   = (ushort*)d_ws;                    // [N, C] bf16
    ushort* edge = xb + (size_t)N_NODES * C;         // [E, C] bf16
    ushort* e1   = edge + (size_t)N_EDGES * C;       // [E, C] bf16

    convert_x_kernel<<<dim3((N_NODES * C) / (256 * 4)), dim3(256), 0, stream>>>(x, xb);
    wconv_kernel<<<dim3(4, 4, 2), dim3(256), 0, stream>>>(W1, W2);

    fused_gather_gemm_kernel<true, false>
        <<<dim3((N_EDGES + BR - 1) / BR), dim3(256), 0, stream>>>(
            xb, seq, 0, edge, nullptr, N_EDGES);

    gemm_mfma_kernel<false><<<dim3((N_EDGES + 127) / 128, 2), dim3(256), 0, stream>>>(
        edge, 1, e1, N_EDGES);

    const int rblk2 = (N_NODES + 127) / 128;   // 128 rows per block now
    gather_node_kernel<<<dim3(4 * rblk2), dim3(1024), 0, stream>>>(
        e1, useq, out, N_NODES);
}

// Round 12
// 277.758 us; speedup vs baseline: 1.4143x; 1.4143x over previous
//
#include <hip/hip_runtime.h>

// Problem constants (match reference setup_inputs)
constexpr int N_NODES = 50000;
constexpr int N_EDGES = 25000;
constexpr int C = 256;   // IN == OUT == 256 channels
constexpr int L = 32;    // incidence list width

// Transposed bf16 weights in device globals.
__device__ ushort W1T_g[C * C];   // [n][k] bf16
__device__ ushort W2T_g[C * C];   // [n][k] bf16

// Native clang vector types (usable with nontemporal builtins).
typedef __attribute__((ext_vector_type(8))) short bf16x8;
typedef __attribute__((ext_vector_type(4))) float f32x4;

__device__ __forceinline__ ushort f2bf(float f) {
    union { float f; unsigned int u; } c; c.f = f;
    unsigned int r = c.u + 0x7FFFu + ((c.u >> 16) & 1u);   // RNE
    return (ushort)(r >> 16);
}
// bf16 pair unpack: low half = shift, high half = mask (1 VALU op each)
__device__ __forceinline__ float bflo(unsigned int u) {
    union { unsigned int x; float f; } c; c.x = u << 16; return c.f;
}
__device__ __forceinline__ float bfhi(unsigned int u) {
    union { unsigned int x; float f; } c; c.x = u & 0xFFFF0000u; return c.f;
}
__device__ __forceinline__ void acc_uint4(float* acc, const uint4 v) {
    acc[0] += bflo(v.x); acc[1] += bfhi(v.x);
    acc[2] += bflo(v.y); acc[3] += bfhi(v.y);
    acc[4] += bflo(v.z); acc[5] += bfhi(v.z);
    acc[6] += bflo(v.w); acc[7] += bfhi(v.w);
}

// ---------------------------------------------------------------------------
// x [N,256] fp32 -> xb bf16. 4 elems/thread.
// ---------------------------------------------------------------------------
__global__ __launch_bounds__(256) void convert_x_kernel(
    const float* __restrict__ x, ushort* __restrict__ xb)
{
    const size_t i = ((size_t)blockIdx.x * 256 + threadIdx.x) * 4;
    const float4 v = *reinterpret_cast<const float4*>(x + i);
    ushort4 o;
    o.x = f2bf(v.x); o.y = f2bf(v.y); o.z = f2bf(v.z); o.w = f2bf(v.w);
    *reinterpret_cast<ushort4*>(xb + i) = o;
}

// ---------------------------------------------------------------------------
// W [256k,256n] fp32 row-major -> WT [n][k] bf16 (transposed), via LDS tile.
// ---------------------------------------------------------------------------
__global__ __launch_bounds__(256) void wconv_kernel(
    const float* __restrict__ W1, const float* __restrict__ W2)
{
    const float* W  = blockIdx.z ? W2 : W1;
    ushort* WT      = blockIdx.z ? W2T_g : W1T_g;
    __shared__ float t[64][65];
    const int rr = threadIdx.x >> 6;    // 0..3
    const int cc = threadIdx.x & 63;    // 0..63
    const int br = blockIdx.x * 64;     // k tile
    const int bc = blockIdx.y * 64;     // n tile
#pragma unroll
    for (int i = 0; i < 16; ++i) {
        const int row = i * 4 + rr;
        t[row][cc] = W[(size_t)(br + row) * C + bc + cc];
    }
    __syncthreads();
#pragma unroll
    for (int i = 0; i < 16; ++i) {
        const int n = i * 4 + rr;
        WT[(size_t)(bc + n) * C + br + cc] = f2bf(t[cc][n]);
    }
}

// ---------------------------------------------------------------------------
// FUSED gather+GEMM (R9/R10-verified; EDGE side only):
//   stage idx -> gather-avg 32 full src rows -> bf16 A-tile [32][264] LDS
//   -> 4 waves MFMA A @ W1T -> RELU+bf16 out.
// (Node-side fusion rejected in R9: losing 64ch chunking pushed 819MB of
// gathers out of L2, FETCH 26MB->282MB, +18us.)
// ---------------------------------------------------------------------------
constexpr int BR = 32;        // output rows per block
constexpr int APITCH = 264;   // bf16 elems per A_lds row (256 + 8 pad)

template <bool RELU, bool OUT_F32>
__global__ __launch_bounds__(256) void fused_gather_gemm_kernel(
    const ushort* __restrict__ src, const int* __restrict__ idx,
    int which_w, ushort* __restrict__ dstb, float* __restrict__ dstf, int M)
{
    const ushort* __restrict__ BT = which_w ? W2T_g : W1T_g;
    const int t  = threadIdx.x;
    const int rb = blockIdx.x * BR;

    __shared__ int    sidx[BR][33];
    __shared__ ushort A_lds[BR][APITCH];

    // ---- stage indices: BR*L = 1024 ints, 4 per thread
#pragma unroll
    for (int i = 0; i < (BR * L) / 256; ++i) {
        const int flat = i * 256 + t;
        const int r = flat >> 5, l = flat & 31;
        sidx[r][l] = (rb + r < M) ? idx[(size_t)(rb + r) * L + l] : 0;
    }
    __syncthreads();

    // ---- gather phase: half-wave (32 lanes) per row, 512B granule, 4 passes
    const int hw = t >> 5;     // 0..7
    const int ln = t & 31;     // channel group: 8 bf16 = 16B per lane

    const uint4 v0 = *reinterpret_cast<const uint4*>(src + ln * 8); // row 0
    float x0[8];
    x0[0] = bflo(v0.x); x0[1] = bfhi(v0.x); x0[2] = bflo(v0.y); x0[3] = bfhi(v0.y);
    x0[4] = bflo(v0.z); x0[5] = bfhi(v0.z); x0[6] = bflo(v0.w); x0[7] = bfhi(v0.w);

#pragma unroll
    for (int p = 0; p < 4; ++p) {
        const int r = p * 8 + hw;
        float acc[8] = {0.f, 0.f, 0.f, 0.f, 0.f, 0.f, 0.f, 0.f};
        int cnt = 0;
#pragma unroll
        for (int lb = 0; lb < L; lb += 8) {
            uint4 v[8];
#pragma unroll
            for (int j = 0; j < 8; ++j) {
                const int id = sidx[r][lb + j];
                cnt += (id > 0) ? 1 : 0;
                v[j] = *reinterpret_cast<const uint4*>(
                    src + (size_t)id * C + ln * 8);
            }
#pragma unroll
            for (int j = 0; j < 8; ++j) acc_uint4(acc, v[j]);
        }
        const float corr = (cnt == 0) ? 0.f : (float)(L - cnt);
        const float inv  = (cnt == 0) ? (1.f / (float)L) : (1.f / (float)cnt);
        uint4 o;
        o.x = (unsigned)f2bf((acc[0] - corr * x0[0]) * inv) |
              ((unsigned)f2bf((acc[1] - corr * x0[1]) * inv) << 16);
        o.y = (unsigned)f2bf((acc[2] - corr * x0[2]) * inv) |
              ((unsigned)f2bf((acc[3] - corr * x0[3]) * inv) << 16);
        o.z = (unsigned)f2bf((acc[4] - corr * x0[4]) * inv) |
              ((unsigned)f2bf((acc[5] - corr * x0[5]) * inv) << 16);
        o.w = (unsigned)f2bf((acc[6] - corr * x0[6]) * inv) |
              ((unsigned)f2bf((acc[7] - corr * x0[7]) * inv) << 16);
        *reinterpret_cast<uint4*>(&A_lds[r][ln * 8]) = o;
    }
    __syncthreads();

    // ---- GEMM phase: wave w covers cols w*64 .. w*64+63
    const int wave = t >> 6;
    const int lane = t & 63;
    const int quad = lane >> 4;
    const int l16  = lane & 15;

    f32x4 acc2[2][4];
    const f32x4 zero = {0.f, 0.f, 0.f, 0.f};
#pragma unroll
    for (int p = 0; p < 2; ++p)
#pragma unroll
        for (int tt = 0; tt < 4; ++tt) acc2[p][tt] = zero;

    const ushort* br = BT + (size_t)(wave * 64 + l16) * C + quad * 8;

#pragma unroll
    for (int k0 = 0; k0 < C; k0 += 32) {
        const bf16x8 a0 = *reinterpret_cast<const bf16x8*>(&A_lds[l16][quad * 8 + k0]);
        const bf16x8 a1 = *reinterpret_cast<const bf16x8*>(&A_lds[16 + l16][quad * 8 + k0]);
#pragma unroll
        for (int tt = 0; tt < 4; ++tt) {
            const bf16x8 b = *reinterpret_cast<const bf16x8*>(
                br + (size_t)tt * 16 * C + k0);
            acc2[0][tt] = __builtin_amdgcn_mfma_f32_16x16x32_bf16(a0, b, acc2[0][tt], 0, 0, 0);
            acc2[1][tt] = __builtin_amdgcn_mfma_f32_16x16x32_bf16(a1, b, acc2[1][tt], 0, 0, 0);
        }
    }

    // ---- epilogue (C/D layout: col=l16, row=quad*4+r -- m89-verified)
#pragma unroll
    for (int p = 0; p < 2; ++p)
#pragma unroll
    for (int tt = 0; tt < 4; ++tt)
#pragma unroll
    for (int r = 0; r < 4; ++r) {
        const int gm = rb + p * 16 + quad * 4 + r;
        if (gm < M) {
            float v = acc2[p][tt][r];
            if (RELU) v = fmaxf(v, 0.f);
            const int col = wave * 64 + tt * 16 + l16;
            if constexpr (OUT_F32) {
                __builtin_nontemporal_store(v, dstf + (size_t)gm * C + col);
            } else {
                dstb[(size_t)gm * C + col] = f2bf(v);
            }
        }
    }
}

// ---------------------------------------------------------------------------
// gather_node: out[row, chunk*64 .. +64] fp32. Chunked (L2-resident slices),
// batch-8 loads, NT stores -- inner loop byte-identical to R8/R10.
// R12 EXPERIMENT: block 512 (8 waves/block, RPB=64). R11's 1024-thread
// variant PROVED occupancy rises with block size (19->35%) but the implied
// VGPR cap (64) spilled the batch-8 pipeline (FETCH/WRITE 335/426MB scratch
// traffic, 200us). At 512 threads (2 waves/SIMD) the VGPR budget holds 96 --
// same experiment without the spill confound.
// GATE: VGPR must stay ~96 and FETCH/WRITE ~26/50MB, else experiment void.
// ---------------------------------------------------------------------------
__global__ __launch_bounds__(512) void gather_node_kernel(
    const ushort* __restrict__ src, const int* __restrict__ idx,
    float* __restrict__ dst, int nrows)
{
    constexpr int BLK = 512;
    constexpr int CH = 64, NCHUNK = 4;
    constexpr int LPR = CH / 8;        // 8 lanes per row
    constexpr int RPB = BLK / LPR;     // 64 rows per block
    const int chunk = blockIdx.x & (NCHUNK - 1);
    const int rb    = (int)(blockIdx.x / NCHUNK) * RPB;
    const int t     = threadIdx.x;

    __shared__ int sidx[RPB][33];
#pragma unroll
    for (int i = 0; i < (RPB * L) / BLK; ++i) {
        const int flat = i * BLK + t;
        const int r = flat >> 5, l = flat & 31;
        sidx[r][l] = (rb + r < nrows) ? idx[(size_t)(rb + r) * L + l] : 0;
    }
    __syncthreads();

    const int r   = t / LPR;
    const int ch  = chunk * CH + (t % LPR) * 8;
    const int row = rb + r;
    if (row >= nrows) return;

    float acc[8] = {0.f, 0.f, 0.f, 0.f, 0.f, 0.f, 0.f, 0.f};
    int cnt = 0;
#pragma unroll
    for (int lb = 0; lb < L; lb += 8) {
        uint4 v[8];
#pragma unroll
        for (int j = 0; j < 8; ++j) {
            const int id = sidx[r][lb + j];
            cnt += (id > 0) ? 1 : 0;
            v[j] = *reinterpret_cast<const uint4*>(
                src + (size_t)id * C + ch);
        }
#pragma unroll
        for (int j = 0; j < 8; ++j) acc_uint4(acc, v[j]);
    }
    const uint4 v0 = *reinterpret_cast<const uint4*>(src + ch);  // row 0
    float x0[8];
    x0[0] = bflo(v0.x); x0[1] = bfhi(v0.x); x0[2] = bflo(v0.y); x0[3] = bfhi(v0.y);
    x0[4] = bflo(v0.z); x0[5] = bfhi(v0.z); x0[6] = bflo(v0.w); x0[7] = bfhi(v0.w);

    const float corr = (cnt == 0) ? 0.f : (float)(L - cnt);
    const float inv  = (cnt == 0) ? (1.f / (float)L) : (1.f / (float)cnt);

    float* d = dst + (size_t)row * C + ch;
    f32x4 o0 = {(acc[0] - corr * x0[0]) * inv, (acc[1] - corr * x0[1]) * inv,
                (acc[2] - corr * x0[2]) * inv, (acc[3] - corr * x0[3]) * inv};
    f32x4 o1 = {(acc[4] - corr * x0[4]) * inv, (acc[5] - corr * x0[5]) * inv,
                (acc[6] - corr * x0[6]) * inv, (acc[7] - corr * x0[7]) * inv};
    __builtin_nontemporal_store(o0, reinterpret_cast<f32x4*>(d));
    __builtin_nontemporal_store(o1, reinterpret_cast<f32x4*>(d) + 1);
}

// ---------------------------------------------------------------------------
// MFMA bf16 GEMM (R8-verified): C[M,256] = A[M,256] @ W, WT bf16 [n][k].
// Wave tile 32x128; grid (ceil(M/128), 2).
// ---------------------------------------------------------------------------
template <bool RELU>
__global__ __launch_bounds__(256) void gemm_mfma_kernel(
    const ushort* __restrict__ A, int which_w,
    ushort* __restrict__ Cmat, int M)
{
    const ushort* __restrict__ BT = which_w ? W2T_g : W1T_g;
    const int wave  = threadIdx.x >> 6;
    const int lane  = threadIdx.x & 63;
    const int quad  = lane >> 4;
    const int l16   = lane & 15;
    const int base  = (blockIdx.x * 4 + wave) * 32;
    const int nbase = blockIdx.y * 128;

    int m0 = base + l16;      if (m0 > M - 1) m0 = M - 1;
    int m1 = base + 16 + l16; if (m1 > M - 1) m1 = M - 1;

    f32x4 acc[2][8];
    const f32x4 zero = {0.f, 0.f, 0.f, 0.f};
#pragma unroll
    for (int p = 0; p < 2; ++p)
#pragma unroll
        for (int t = 0; t < 8; ++t) acc[p][t] = zero;

    const ushort* a0 = A + (size_t)m0 * C + quad * 8;
    const ushort* a1 = A + (size_t)m1 * C + quad * 8;
    const ushort* br = BT + (size_t)(nbase + l16) * C + quad * 8;

#pragma unroll
    for (int k0 = 0; k0 < C; k0 += 32) {
        const bf16x8 av0 = *reinterpret_cast<const bf16x8*>(a0 + k0);
        const bf16x8 av1 = *reinterpret_cast<const bf16x8*>(a1 + k0);
#pragma unroll
        for (int t = 0; t < 8; ++t) {
            const bf16x8 b = *reinterpret_cast<const bf16x8*>(
                br + (size_t)t * 16 * C + k0);
            acc[0][t] = __builtin_amdgcn_mfma_f32_16x16x32_bf16(av0, b, acc[0][t], 0, 0, 0);
            acc[1][t] = __builtin_amdgcn_mfma_f32_16x16x32_bf16(av1, b, acc[1][t], 0, 0, 0);
        }
    }

#pragma unroll
    for (int p = 0; p < 2; ++p)
#pragma unroll
    for (int t = 0; t < 8; ++t)
#pragma unroll
    for (int r = 0; r < 4; ++r) {
        const int gm = base + p * 16 + quad * 4 + r;
        if (gm < M) {
            float v = acc[p][t][r];
            if (RELU) v = fmaxf(v, 0.f);
            Cmat[(size_t)gm * C + nbase + t * 16 + l16] = f2bf(v);
        }
    }
}

// ---------------------------------------------------------------------------
// Pipeline (R10 hybrid + R12 gather_node 512-thread experiment):
//   xb   = bf16(x)                                   [N,256]
//   edge = relu(avg(xb[seq]) @ W1)                   [E,256] bf16  (FUSED)
//   e1   = edge @ W2                                 [E,256] bf16  (GEMM)
//   out  = avg(e1[useq])                             [N,256] fp32  (chunked)
// ws: xb 25.6MB + edge 12.8MB + e1 12.8MB = 51.2MB. 5 dispatches.
// ---------------------------------------------------------------------------
extern "C" void kernel_launch(void* const* d_in, const int* in_sizes, int n_in,
                              void* d_out, int out_size, void* d_ws, size_t ws_size,
                              hipStream_t stream) {
    const float* x    = (const float*)d_in[0];
    const int*   seq  = (const int*)d_in[1];
    const int*   useq = (const int*)d_in[2];
    const float* W1   = (const float*)d_in[3];
    const float* W2   = (const float*)d_in[4];
    float* out = (float*)d_out;

    ushort* xb   = (ushort*)d_ws;                    // [N, C] bf16
    ushort* edge = xb + (size_t)N_NODES * C;         // [E, C] bf16
    ushort* e1   = edge + (size_t)N_EDGES * C;       // [E, C] bf16

    convert_x_kernel<<<dim3((N_NODES * C) / (256 * 4)), dim3(256), 0, stream>>>(x, xb);
    wconv_kernel<<<dim3(4, 4, 2), dim3(256), 0, stream>>>(W1, W2);

    fused_gather_gemm_kernel<true, false>
        <<<dim3((N_EDGES + BR - 1) / BR), dim3(256), 0, stream>>>(
            xb, seq, 0, edge, nullptr, N_EDGES);

    gemm_mfma_kernel<false><<<dim3((N_EDGES + 127) / 128, 2), dim3(256), 0, stream>>>(
        edge, 1, e1, N_EDGES);

    const int rblk2 = (N_NODES + 63) / 64;   // 64 rows per block at 512 thr
    gather_node_kernel<<<dim3(4 * rblk2), dim3(512), 0, stream>>>(
        e1, useq, out, N_NODES);
}

// Round 13
// 267.485 us; speedup vs baseline: 1.4687x; 1.0384x over previous
//
#include <hip/hip_runtime.h>

// Problem constants (match reference setup_inputs)
constexpr int N_NODES = 50000;
constexpr int N_EDGES = 25000;
constexpr int C = 256;   // IN == OUT == 256 channels
constexpr int L = 32;    // incidence list width

// Transposed bf16 weights in device globals.
__device__ ushort W1T_g[C * C];   // [n][k] bf16
__device__ ushort W2T_g[C * C];   // [n][k] bf16

// Native clang vector types (usable with nontemporal builtins).
typedef __attribute__((ext_vector_type(8))) short bf16x8;
typedef __attribute__((ext_vector_type(4))) float f32x4;

__device__ __forceinline__ ushort f2bf(float f) {
    union { float f; unsigned int u; } c; c.f = f;
    unsigned int r = c.u + 0x7FFFu + ((c.u >> 16) & 1u);   // RNE
    return (ushort)(r >> 16);
}
// bf16 pair unpack: low half = shift, high half = mask (1 VALU op each)
__device__ __forceinline__ float bflo(unsigned int u) {
    union { unsigned int x; float f; } c; c.x = u << 16; return c.f;
}
__device__ __forceinline__ float bfhi(unsigned int u) {
    union { unsigned int x; float f; } c; c.x = u & 0xFFFF0000u; return c.f;
}
__device__ __forceinline__ void acc_uint4(float* acc, const uint4 v) {
    acc[0] += bflo(v.x); acc[1] += bfhi(v.x);
    acc[2] += bflo(v.y); acc[3] += bfhi(v.y);
    acc[4] += bflo(v.z); acc[5] += bfhi(v.z);
    acc[6] += bflo(v.w); acc[7] += bfhi(v.w);
}

// ---------------------------------------------------------------------------
// MERGED prep kernel (R13): blocks [0, NCONV) convert x fp32->bf16 (4/thread);
// blocks [NCONV, NCONV+32) transpose W1/W2 -> bf16 WT via LDS tile.
// Merging saves one dispatch + drain; the 16.6KB LDS still allows 8+
// blocks/CU so the streaming convert path loses no occupancy.
// ---------------------------------------------------------------------------
constexpr int NCONV = (N_NODES * C) / (256 * 4);   // 12500 convert blocks

__global__ __launch_bounds__(256) void prep_kernel(
    const float* __restrict__ x, ushort* __restrict__ xb,
    const float* __restrict__ W1, const float* __restrict__ W2)
{
    __shared__ float t[64][65];
    const int bid = blockIdx.x;
    if (bid < NCONV) {
        const size_t i = ((size_t)bid * 256 + threadIdx.x) * 4;
        const float4 v = *reinterpret_cast<const float4*>(x + i);
        ushort4 o;
        o.x = f2bf(v.x); o.y = f2bf(v.y); o.z = f2bf(v.z); o.w = f2bf(v.w);
        *reinterpret_cast<ushort4*>(xb + i) = o;
        return;
    }
    const int wb  = bid - NCONV;        // 0..31
    const int wz  = wb >> 4;            // which W
    const int rem = wb & 15;
    const int br  = (rem & 3) * 64;     // k tile
    const int bc  = (rem >> 2) * 64;    // n tile
    const float* W = wz ? W2 : W1;
    ushort* WT     = wz ? W2T_g : W1T_g;
    const int rr = threadIdx.x >> 6;    // 0..3
    const int cc = threadIdx.x & 63;    // 0..63
#pragma unroll
    for (int i = 0; i < 16; ++i) {
        const int row = i * 4 + rr;
        t[row][cc] = W[(size_t)(br + row) * C + bc + cc];
    }
    __syncthreads();
#pragma unroll
    for (int i = 0; i < 16; ++i) {
        const int n = i * 4 + rr;
        WT[(size_t)(bc + n) * C + br + cc] = f2bf(t[cc][n]);
    }
}

// ---------------------------------------------------------------------------
// FUSED gather+GEMM (R9/R10-verified; EDGE side only):
//   stage idx -> gather-avg 32 full src rows -> bf16 A-tile [32][264] LDS
//   -> 4 waves MFMA A @ W1T -> RELU+bf16 out.
// (Node-side fusion rejected in R9: losing 64ch chunking pushed 819MB of
// gathers out of L2, FETCH 26MB->282MB, +18us.)
// ---------------------------------------------------------------------------
constexpr int BR = 32;        // output rows per block
constexpr int APITCH = 264;   // bf16 elems per A_lds row (256 + 8 pad)

template <bool RELU, bool OUT_F32>
__global__ __launch_bounds__(256) void fused_gather_gemm_kernel(
    const ushort* __restrict__ src, const int* __restrict__ idx,
    int which_w, ushort* __restrict__ dstb, float* __restrict__ dstf, int M)
{
    const ushort* __restrict__ BT = which_w ? W2T_g : W1T_g;
    const int t  = threadIdx.x;
    const int rb = blockIdx.x * BR;

    __shared__ int    sidx[BR][33];
    __shared__ ushort A_lds[BR][APITCH];

    // ---- stage indices: BR*L = 1024 ints, 4 per thread
#pragma unroll
    for (int i = 0; i < (BR * L) / 256; ++i) {
        const int flat = i * 256 + t;
        const int r = flat >> 5, l = flat & 31;
        sidx[r][l] = (rb + r < M) ? idx[(size_t)(rb + r) * L + l] : 0;
    }
    __syncthreads();

    // ---- gather phase: half-wave (32 lanes) per row, 512B granule, 4 passes
    const int hw = t >> 5;     // 0..7
    const int ln = t & 31;     // channel group: 8 bf16 = 16B per lane

    const uint4 v0 = *reinterpret_cast<const uint4*>(src + ln * 8); // row 0
    float x0[8];
    x0[0] = bflo(v0.x); x0[1] = bfhi(v0.x); x0[2] = bflo(v0.y); x0[3] = bfhi(v0.y);
    x0[4] = bflo(v0.z); x0[5] = bfhi(v0.z); x0[6] = bflo(v0.w); x0[7] = bfhi(v0.w);

#pragma unroll
    for (int p = 0; p < 4; ++p) {
        const int r = p * 8 + hw;
        float acc[8] = {0.f, 0.f, 0.f, 0.f, 0.f, 0.f, 0.f, 0.f};
        int cnt = 0;
#pragma unroll
        for (int lb = 0; lb < L; lb += 8) {
            uint4 v[8];
#pragma unroll
            for (int j = 0; j < 8; ++j) {
                const int id = sidx[r][lb + j];
                cnt += (id > 0) ? 1 : 0;
                v[j] = *reinterpret_cast<const uint4*>(
                    src + (size_t)id * C + ln * 8);
            }
#pragma unroll
            for (int j = 0; j < 8; ++j) acc_uint4(acc, v[j]);
        }
        const float corr = (cnt == 0) ? 0.f : (float)(L - cnt);
        const float inv  = (cnt == 0) ? (1.f / (float)L) : (1.f / (float)cnt);
        uint4 o;
        o.x = (unsigned)f2bf((acc[0] - corr * x0[0]) * inv) |
              ((unsigned)f2bf((acc[1] - corr * x0[1]) * inv) << 16);
        o.y = (unsigned)f2bf((acc[2] - corr * x0[2]) * inv) |
              ((unsigned)f2bf((acc[3] - corr * x0[3]) * inv) << 16);
        o.z = (unsigned)f2bf((acc[4] - corr * x0[4]) * inv) |
              ((unsigned)f2bf((acc[5] - corr * x0[5]) * inv) << 16);
        o.w = (unsigned)f2bf((acc[6] - corr * x0[6]) * inv) |
              ((unsigned)f2bf((acc[7] - corr * x0[7]) * inv) << 16);
        *reinterpret_cast<uint4*>(&A_lds[r][ln * 8]) = o;
    }
    __syncthreads();

    // ---- GEMM phase: wave w covers cols w*64 .. w*64+63
    const int wave = t >> 6;
    const int lane = t & 63;
    const int quad = lane >> 4;
    const int l16  = lane & 15;

    f32x4 acc2[2][4];
    const f32x4 zero = {0.f, 0.f, 0.f, 0.f};
#pragma unroll
    for (int p = 0; p < 2; ++p)
#pragma unroll
        for (int tt = 0; tt < 4; ++tt) acc2[p][tt] = zero;

    const ushort* br = BT + (size_t)(wave * 64 + l16) * C + quad * 8;

#pragma unroll
    for (int k0 = 0; k0 < C; k0 += 32) {
        const bf16x8 a0 = *reinterpret_cast<const bf16x8*>(&A_lds[l16][quad * 8 + k0]);
        const bf16x8 a1 = *reinterpret_cast<const bf16x8*>(&A_lds[16 + l16][quad * 8 + k0]);
#pragma unroll
        for (int tt = 0; tt < 4; ++tt) {
            const bf16x8 b = *reinterpret_cast<const bf16x8*>(
                br + (size_t)tt * 16 * C + k0);
            acc2[0][tt] = __builtin_amdgcn_mfma_f32_16x16x32_bf16(a0, b, acc2[0][tt], 0, 0, 0);
            acc2[1][tt] = __builtin_amdgcn_mfma_f32_16x16x32_bf16(a1, b, acc2[1][tt], 0, 0, 0);
        }
    }

    // ---- epilogue (C/D layout: col=l16, row=quad*4+r -- m89-verified)
#pragma unroll
    for (int p = 0; p < 2; ++p)
#pragma unroll
    for (int tt = 0; tt < 4; ++tt)
#pragma unroll
    for (int r = 0; r < 4; ++r) {
        const int gm = rb + p * 16 + quad * 4 + r;
        if (gm < M) {
            float v = acc2[p][tt][r];
            if (RELU) v = fmaxf(v, 0.f);
            const int col = wave * 64 + tt * 16 + l16;
            if constexpr (OUT_F32) {
                __builtin_nontemporal_store(v, dstf + (size_t)gm * C + col);
            } else {
                dstb[(size_t)gm * C + col] = f2bf(v);
            }
        }
    }
}

// ---------------------------------------------------------------------------
// gather_node (R10-verified BEST: 76.6us): out[row, chunk*64 .. +64] fp32.
// 256 threads, static chunk map (blockIdx&3), 128B granule (3.2MB L2 slice),
// batch-8 loads, NT stores. R11/R12 closed the occupancy theory: 512/1024-
// thread variants raise occupancy but run SLOWER (84/200us) -- the in-flight
// line cap (~48/CU) is a per-CU hardware limit, not wave-count. This config
// is the measured floor for the pattern.
// ---------------------------------------------------------------------------
__global__ __launch_bounds__(256) void gather_node_kernel(
    const ushort* __restrict__ src, const int* __restrict__ idx,
    float* __restrict__ dst, int nrows)
{
    constexpr int CH = 64, NCHUNK = 4;
    constexpr int LPR = CH / 8;        // 8 lanes per row
    constexpr int RPB = 256 / LPR;     // 32 rows per block
    const int chunk = blockIdx.x & (NCHUNK - 1);
    const int rb    = (int)(blockIdx.x / NCHUNK) * RPB;
    const int t     = threadIdx.x;

    __shared__ int sidx[RPB][33];
#pragma unroll
    for (int i = 0; i < (RPB * L) / 256; ++i) {
        const int flat = i * 256 + t;
        const int r = flat >> 5, l = flat & 31;
        sidx[r][l] = (rb + r < nrows) ? idx[(size_t)(rb + r) * L + l] : 0;
    }
    __syncthreads();

    const int r   = t / LPR;
    const int ch  = chunk * CH + (t % LPR) * 8;
    const int row = rb + r;
    if (row >= nrows) return;

    float acc[8] = {0.f, 0.f, 0.f, 0.f, 0.f, 0.f, 0.f, 0.f};
    int cnt = 0;
#pragma unroll
    for (int lb = 0; lb < L; lb += 8) {
        uint4 v[8];
#pragma unroll
        for (int j = 0; j < 8; ++j) {
            const int id = sidx[r][lb + j];
            cnt += (id > 0) ? 1 : 0;
            v[j] = *reinterpret_cast<const uint4*>(
                src + (size_t)id * C + ch);
        }
#pragma unroll
        for (int j = 0; j < 8; ++j) acc_uint4(acc, v[j]);
    }
    const uint4 v0 = *reinterpret_cast<const uint4*>(src + ch);  // row 0
    float x0[8];
    x0[0] = bflo(v0.x); x0[1] = bfhi(v0.x); x0[2] = bflo(v0.y); x0[3] = bfhi(v0.y);
    x0[4] = bflo(v0.z); x0[5] = bfhi(v0.z); x0[6] = bflo(v0.w); x0[7] = bfhi(v0.w);

    const float corr = (cnt == 0) ? 0.f : (float)(L - cnt);
    const float inv  = (cnt == 0) ? (1.f / (float)L) : (1.f / (float)cnt);

    float* d = dst + (size_t)row * C + ch;
    f32x4 o0 = {(acc[0] - corr * x0[0]) * inv, (acc[1] - corr * x0[1]) * inv,
                (acc[2] - corr * x0[2]) * inv, (acc[3] - corr * x0[3]) * inv};
    f32x4 o1 = {(acc[4] - corr * x0[4]) * inv, (acc[5] - corr * x0[5]) * inv,
                (acc[6] - corr * x0[6]) * inv, (acc[7] - corr * x0[7]) * inv};
    __builtin_nontemporal_store(o0, reinterpret_cast<f32x4*>(d));
    __builtin_nontemporal_store(o1, reinterpret_cast<f32x4*>(d) + 1);
}

// ---------------------------------------------------------------------------
// MFMA bf16 GEMM (R8-verified): C[M,256] = A[M,256] @ W, WT bf16 [n][k].
// Wave tile 32x128; grid (ceil(M/128), 2).
// ---------------------------------------------------------------------------
template <bool RELU>
__global__ __launch_bounds__(256) void gemm_mfma_kernel(
    const ushort* __restrict__ A, int which_w,
    ushort* __restrict__ Cmat, int M)
{
    const ushort* __restrict__ BT = which_w ? W2T_g : W1T_g;
    const int wave  = threadIdx.x >> 6;
    const int lane  = threadIdx.x & 63;
    const int quad  = lane >> 4;
    const int l16   = lane & 15;
    const int base  = (blockIdx.x * 4 + wave) * 32;
    const int nbase = blockIdx.y * 128;

    int m0 = base + l16;      if (m0 > M - 1) m0 = M - 1;
    int m1 = base + 16 + l16; if (m1 > M - 1) m1 = M - 1;

    f32x4 acc[2][8];
    const f32x4 zero = {0.f, 0.f, 0.f, 0.f};
#pragma unroll
    for (int p = 0; p < 2; ++p)
#pragma unroll
        for (int t = 0; t < 8; ++t) acc[p][t] = zero;

    const ushort* a0 = A + (size_t)m0 * C + quad * 8;
    const ushort* a1 = A + (size_t)m1 * C + quad * 8;
    const ushort* br = BT + (size_t)(nbase + l16) * C + quad * 8;

#pragma unroll
    for (int k0 = 0; k0 < C; k0 += 32) {
        const bf16x8 av0 = *reinterpret_cast<const bf16x8*>(a0 + k0);
        const bf16x8 av1 = *reinterpret_cast<const bf16x8*>(a1 + k0);
#pragma unroll
        for (int t = 0; t < 8; ++t) {
            const bf16x8 b = *reinterpret_cast<const bf16x8*>(
                br + (size_t)t * 16 * C + k0);
            acc[0][t] = __builtin_amdgcn_mfma_f32_16x16x32_bf16(av0, b, acc[0][t], 0, 0, 0);
            acc[1][t] = __builtin_amdgcn_mfma_f32_16x16x32_bf16(av1, b, acc[1][t], 0, 0, 0);
        }
    }

#pragma unroll
    for (int p = 0; p < 2; ++p)
#pragma unroll
    for (int t = 0; t < 8; ++t)
#pragma unroll
    for (int r = 0; r < 4; ++r) {
        const int gm = base + p * 16 + quad * 4 + r;
        if (gm < M) {
            float v = acc[p][t][r];
            if (RELU) v = fmaxf(v, 0.f);
            Cmat[(size_t)gm * C + nbase + t * 16 + l16] = f2bf(v);
        }
    }
}

// ---------------------------------------------------------------------------
// Pipeline (R13 = R10 best config + merged prep):
//   xb   = bf16(x); WT = bf16(W^T)                   (MERGED prep)
//   edge = relu(avg(xb[seq]) @ W1)                   [E,256] bf16  (FUSED)
//   e1   = edge @ W2                                 [E,256] bf16  (GEMM)
//   out  = avg(e1[useq])                             [N,256] fp32  (chunked)
// ws: xb 25.6MB + edge 12.8MB + e1 12.8MB = 51.2MB. 4 dispatches.
// ---------------------------------------------------------------------------
extern "C" void kernel_launch(void* const* d_in, const int* in_sizes, int n_in,
                              void* d_out, int out_size, void* d_ws, size_t ws_size,
                              hipStream_t stream) {
    const float* x    = (const float*)d_in[0];
    const int*   seq  = (const int*)d_in[1];
    const int*   useq = (const int*)d_in[2];
    const float* W1   = (const float*)d_in[3];
    const float* W2   = (const float*)d_in[4];
    float* out = (float*)d_out;

    ushort* xb   = (ushort*)d_ws;                    // [N, C] bf16
    ushort* edge = xb + (size_t)N_NODES * C;         // [E, C] bf16
    ushort* e1   = edge + (size_t)N_EDGES * C;       // [E, C] bf16

    prep_kernel<<<dim3(NCONV + 32), dim3(256), 0, stream>>>(x, xb, W1, W2);

    fused_gather_gemm_kernel<true, false>
        <<<dim3((N_EDGES + BR - 1) / BR), dim3(256), 0, stream>>>(
            xb, seq, 0, edge, nullptr, N_EDGES);

    gemm_mfma_kernel<false><<<dim3((N_EDGES + 127) / 128, 2), dim3(256), 0, stream>>>(
        edge, 1, e1, N_EDGES);

    const int rblk2 = (N_NODES + 31) / 32;
    gather_node_kernel<<<dim3(4 * rblk2), dim3(256), 0, stream>>>(
        e1, useq, out, N_NODES);
}